// Round 10
// baseline (36.499 us; speedup 1.0000x reference)
//
#include <hip/hip_runtime.h>
#include <hip/hip_bf16.h>

typedef float    f32x4 __attribute__((ext_vector_type(4)));
typedef _Float16 f16x4 __attribute__((ext_vector_type(4)));
typedef _Float16 f16x8 __attribute__((ext_vector_type(8)));
typedef unsigned int   u32x4 __attribute__((ext_vector_type(4)));

#define NB 32
#define NA 64
#define NF 128
#define NC 128

// ---------------------------------------------------------------------------
// prep (unchanged from R9, MFMA-based):
//  blocks 0..255 : u/v for 16 atoms of (b,g) via mfma_f32_16x16x32_f16.
//  blocks 256..263: w1f in MFMA A-fragment order.
// ---------------------------------------------------------------------------
__global__ __launch_bounds__(256) void prep_kernel(
    const float* __restrict__ x, const float* __restrict__ W0,
    const float* __restrict__ b0, const float* __restrict__ W1,
    _Float16* __restrict__ u, _Float16* __restrict__ v,
    _Float16* __restrict__ w1f)
{
    int blk = blockIdx.x, tid = threadIdx.x;
    if (blk < 256) {
        __shared__ __align__(16) _Float16 w0h[32 * 64 * 8];  // 32 KB frag-major
        int b = blk >> 3, g = (blk >> 1) & 3, half = blk & 1;

        int lane = tid & 63, wave = tid >> 6;
        int llo = lane & 15, lhi = lane >> 4;

        const float* xrow = x + ((size_t)b * NA + g * 16 + llo) * NF;
        f16x8 xf[4];
        #pragma unroll
        for (int kk = 0; kk < 4; ++kk) {
            f32x4 a0 = *(const f32x4*)(xrow + kk * 32 + lhi * 8);
            f32x4 a1 = *(const f32x4*)(xrow + kk * 32 + lhi * 8 + 4);
            #pragma unroll
            for (int e = 0; e < 4; ++e) {
                xf[kk][e]     = (_Float16)a0[e];
                xf[kk][e + 4] = (_Float16)a1[e];
            }
        }

        #pragma unroll
        for (int p = 0; p < 8; ++p) {
            int sl   = p * 256 + tid;
            int frag = sl >> 6;
            int ln   = sl & 63;
            int kk   = frag >> 3, nfc = frag & 7;
            int k0   = half * 128 + kk * 32 + (ln >> 4) * 8;
            int c    = nfc * 16 + (ln & 15);
            f16x8 o;
            #pragma unroll
            for (int e = 0; e < 8; ++e)
                o[e] = (_Float16)W0[(size_t)(k0 + e) * NC + c];
            *(f16x8*)(w0h + (size_t)sl * 8) = o;
        }
        __syncthreads();

        f32x4 acc[2];
        f32x4 z = {0.f, 0.f, 0.f, 0.f};
        acc[0] = z; acc[1] = z;
        #pragma unroll
        for (int kk = 0; kk < 4; ++kk) {
            #pragma unroll
            for (int t = 0; t < 2; ++t) {
                int nfc = wave * 2 + t;
                f16x8 aw = *(const f16x8*)(w0h +
                    (size_t)((kk * 8 + nfc) * 64 + lane) * 8);
                acc[t] = __builtin_amdgcn_mfma_f32_16x16x32_f16(
                    aw, xf[kk], acc[t], 0, 0, 0);
            }
        }

        _Float16* dst = half ? v : u;
        size_t arow = ((size_t)b * NA + g * 16 + llo) * NC;
        #pragma unroll
        for (int t = 0; t < 2; ++t) {
            int nfc = wave * 2 + t;
            int c0  = nfc * 16 + lhi * 4;
            f16x4 o;
            if (half) {
                f32x4 bb = *(const f32x4*)(b0 + c0);
                #pragma unroll
                for (int e = 0; e < 4; ++e)
                    o[e] = (_Float16)(acc[t][e] + bb[e]);
            } else {
                #pragma unroll
                for (int e = 0; e < 4; ++e)
                    o[e] = (_Float16)acc[t][e];
            }
            *(f16x4*)(dst + arow + c0) = o;
        }
    } else {
        int fl   = (blk - 256) * 256 + tid;   // 0..2047
        int lane = fl & 63;
        int frag = fl >> 6;                   // kk*8+nf
        int kk = frag >> 3, nf = frag & 7;
        int k0 = kk * 32 + (lane >> 4) * 8;
        int n  = nf * 16 + (lane & 15);
        f16x8 o;
        #pragma unroll
        for (int e = 0; e < 8; ++e)
            o[e] = (_Float16)W1[(size_t)(k0 + e) * NC + n];
        *(f16x8*)(w1f + (size_t)fl * 8) = o;
    }
}

// ---------------------------------------------------------------------------
// main: block = (batch b, i-slab Iq of 8 rows), 256 blocks x 512 thr, 1/CU.
// Wave w owns i = Iq*8+w; 4 tasks j0 = q*16. No mirror: out slab of the block
// is 256KB contiguous. u/v for all 64 atoms in LDS (32KB, XOR-swizzled);
// W1 frags hoisted global->regs once (latency hidden behind staging).
// ---------------------------------------------------------------------------
__global__ __launch_bounds__(512, 2) void pair_mlp_kernel(
    const float* __restrict__ b1g, const _Float16* __restrict__ u,
    const _Float16* __restrict__ v, const _Float16* __restrict__ w1f,
    float* __restrict__ out)
{
    __shared__ __align__(16) _Float16 u_s[64 * 128];   // 16 KB swizzled
    __shared__ __align__(16) _Float16 v_s[64 * 128];   // 16 KB

    int blk = blockIdx.x;
    int b  = blk >> 3;
    int Iq = blk & 7;
    int tid  = threadIdx.x;
    int wave = tid >> 6, lane = tid & 63;
    int llo  = lane & 15, lhi = lane >> 4;

    // ---- hoist W1 fragments -> 128 VGPRs (issued first; one-shot)
    f16x8 wreg[4][8];
    #pragma unroll
    for (int kk = 0; kk < 4; ++kk)
        #pragma unroll
        for (int nf = 0; nf < 8; ++nf)
            wreg[kk][nf] = ((const f16x8*)w1f)[(kk * 8 + nf) * 64 + lane];

    // ---- stage u/v for all 64 atoms of batch b (swizzled 16B chunks)
    #pragma unroll
    for (int p = 0; p < 2; ++p) {
        int idx = p * 512 + tid;        // 0..1023
        int row = idx >> 4;             // atom 0..63
        int c   = idx & 15;             // 16B chunk in 256B row
        int sc  = row * 16 + (c ^ (row & 7));
        ((u32x4*)u_s)[sc] = ((const u32x4*)(u + ((size_t)b * NA + row) * NC))[c];
        ((u32x4*)v_s)[sc] = ((const u32x4*)(v + ((size_t)b * NA + row) * NC))[c];
    }
    __syncthreads();

    int ai = Iq * 8 + wave;             // this wave's i atom (ai&7 == wave)
    const f16x8* us = (const f16x8*)u_s;
    const f16x8* vs = (const f16x8*)v_s;
    float* orow = out + ((size_t)b * 4096 + (size_t)ai * 64) * 128;

    f32x4 z = {0.f, 0.f, 0.f, 0.f};

    for (int q = 0; q < 4; ++q) {
        int aj = q * 16 + llo;          // aj&7 == llo&7

        f32x4 acc0[8], acc1[8];
        #pragma unroll
        for (int nf = 0; nf < 8; ++nf) { acc0[nf] = z; acc1[nf] = z; }

        #pragma unroll
        for (int kk = 0; kk < 4; ++kk) {
            int kc  = kk * 4 + lhi;
            int sci = ai * 16 + (kc ^ (ai & 7));
            int scj = aj * 16 + (kc ^ (aj & 7));

            f16x8 ui = us[sci];         // uniform across llo (broadcast)
            f16x8 vi = vs[sci];
            f16x8 uj = us[scj];
            f16x8 vj = vs[scj];

            f16x8 s0 = ui + vj;         // h(i,j) pre-relu
            f16x8 s1 = uj + vi;         // h(j,i) pre-relu
            f16x8 h0, h1;
            #pragma unroll
            for (int e = 0; e < 8; ++e) {
                h0[e] = s0[e] < (_Float16)0 ? (_Float16)0 : s0[e];
                h1[e] = s1[e] < (_Float16)0 ? (_Float16)0 : s1[e];
            }

            #pragma unroll
            for (int nf = 0; nf < 8; ++nf) {
                acc0[nf] = __builtin_amdgcn_mfma_f32_16x16x32_f16(
                    wreg[kk][nf], h0, acc0[nf], 0, 0, 0);
                acc1[nf] = __builtin_amdgcn_mfma_f32_16x16x32_f16(
                    wreg[kk][nf], h1, acc1[nf], 0, 0, 0);
            }
        }

        // epilogue: lane llo = j, n = nf*16 + lhi*4 + e; contiguous slab
        float* p1 = orow + (size_t)(q * 16 + llo) * 128 + lhi * 4;
        #pragma unroll
        for (int nf = 0; nf < 8; ++nf) {
            f32x4 bias = *(const f32x4*)(b1g + nf * 16 + lhi * 4);
            f32x4 val;
            #pragma unroll
            for (int e = 0; e < 4; ++e)
                val[e] = fmaxf(acc0[nf][e] + bias[e], 0.f) +
                         fmaxf(acc1[nf][e] + bias[e], 0.f);
            *(f32x4*)(p1 + nf * 16) = val;
        }
    }
}

extern "C" void kernel_launch(void* const* d_in, const int* in_sizes, int n_in,
                              void* d_out, int out_size, void* d_ws, size_t ws_size,
                              hipStream_t stream)
{
    (void)in_sizes; (void)n_in; (void)out_size; (void)ws_size;
    const float* x  = (const float*)d_in[0];
    const float* W0 = (const float*)d_in[1];
    const float* b0 = (const float*)d_in[2];
    const float* W1 = (const float*)d_in[3];
    const float* b1 = (const float*)d_in[4];
    float* out = (float*)d_out;

    _Float16* u   = (_Float16*)d_ws;                       // 0.5 MB
    _Float16* v   = u + (size_t)NB * NA * NC;              // 0.5 MB
    _Float16* w1f = v + (size_t)NB * NA * NC;              // 32 KB

    prep_kernel<<<264, 256, 0, stream>>>(x, W0, b0, W1, u, v, w1f);
    pair_mlp_kernel<<<NB * 8, 512, 0, stream>>>(b1, u, v, w1f, out);
}